// Round 6
// baseline (212.409 us; speedup 1.0000x reference)
//
#include <hip/hip_runtime.h>

// YOLO loss: pred/target (4096, 30, 14, 14) f32 -> scalar. ~193 MB read.
// R6: byte-partitioned experiment. R1-R5 all plateau at ~2.7 TB/s total-read
// regardless of structure; R4's L3-resident dispatch (zero HBM fetch) took the
// SAME 70 us -> not HBM-bound. Remaining theories: (1) read-direction ceiling
// ~3.15 TB/s (half of m13's 6.29 copy), (2) access-structure penalty.
// This round: class planes (129 MB, 2/3 of bytes) as a PURE grid-stride
// float4 stream (copy-clone shape) + L1-hot obj side-load; box planes (64 MB)
// as R1's verified per-cell-quad gather. Separate dispatches -> separate
// counters decide between theories.

#define S_GRID 14
#define SS 196              // S*S
#define N_BATCH 4096
#define QPI 1470            // quads per image (30 planes * 49)
#define CQ_PER_IMG 980      // class quads per image (planes 10..29)
#define NCQ (N_BATCH * CQ_PER_IMG)   // 4,014,080
#define NBQ (N_BATCH * 49)           // 200,704 box cell-quads
#define CLS_BLOCKS 2048
#define BOX_BLOCKS 784               // NBQ / 256 exactly
#define NPART (CLS_BLOCKS + BOX_BLOCKS)   // 2832
#define LAMBDA_COORD 5.0f
#define LAMBDA_NOOBJ 0.5f

// ---------------- class kernel: pure stream ----------------
__global__ __launch_bounds__(256) void cls_kernel(
    const float* __restrict__ pred,
    const float* __restrict__ tgt,
    float* __restrict__ part)
{
    const float4* pb4 = (const float4*)pred;
    const float4* tb4 = (const float4*)tgt;
    const int gtid   = blockIdx.x * 256 + threadIdx.x;
    const int stride = CLS_BLOCKS * 256;

    float total = 0.f;
    for (int q = gtid; q < NCQ; q += stride) {
        const int n  = q / CQ_PER_IMG;
        const int r  = q - n * CQ_PER_IMG;
        const int rq = r - 49 * (r / 49);          // quad within its plane
        const size_t base = (size_t)n * QPI;
        const float4 p = pb4[base + 490 + r];
        const float4 t = tb4[base + 490 + r];
        const float4 o = tb4[base + 196 + rq];     // tgt conf plane (d=4), L1-hot
        const float d0 = p.x - t.x, d1 = p.y - t.y;
        const float d2 = p.z - t.z, d3 = p.w - t.w;
        const float a0 = (o.x > 0.f) ? d0 * d0 : 0.f;
        const float a1 = (o.y > 0.f) ? d1 * d1 : 0.f;
        const float a2 = (o.z > 0.f) ? d2 * d2 : 0.f;
        const float a3 = (o.w > 0.f) ? d3 * d3 : 0.f;
        total += (a0 + a1) + (a2 + a3);
    }

#pragma unroll
    for (int off = 32; off > 0; off >>= 1)
        total += __shfl_down(total, off);
    __shared__ float wsum[4];
    if ((threadIdx.x & 63) == 0) wsum[threadIdx.x >> 6] = total;
    __syncthreads();
    if (threadIdx.x == 0)
        part[blockIdx.x] = (wsum[0] + wsum[1]) + (wsum[2] + wsum[3]);
}

// ---------------- box kernel: per-cell-quad gather (R1 math, verified) ----
__global__ __launch_bounds__(256) void box_kernel(
    const float* __restrict__ pred,
    const float* __restrict__ tgt,
    float* __restrict__ part)
{
    const int t  = blockIdx.x * 256 + threadIdx.x;   // cell-quad in [0, NBQ)
    const int n  = t / 49;
    const int q  = t - n * 49;

    const float4* pb = (const float4*)pred + (size_t)n * QPI + q;
    const float4* tb = (const float4*)tgt  + (size_t)n * QPI + q;

    float P[10][4], T[10][4];
#pragma unroll
    for (int d = 0; d < 10; ++d) {
        const float4 p  = pb[d * 49];
        const float4 tv = tb[d * 49];
        P[d][0] = p.x;  P[d][1] = p.y;  P[d][2] = p.z;  P[d][3] = p.w;
        T[d][0] = tv.x; T[d][1] = tv.y; T[d][2] = tv.z; T[d][3] = tv.w;
    }

    float total = 0.f;
#pragma unroll
    for (int j = 0; j < 4; ++j) {
        const float tconf = T[4][j];
        const float obj   = (tconf > 0.f)  ? 1.f : 0.f;
        const float noobj = (tconf == 0.f) ? 1.f : 0.f;

        const float dc0 = P[4][j] - T[4][j];
        const float dc1 = P[9][j] - T[9][j];
        const float noobj_term = noobj * (dc0 * dc0 + dc1 * dc1);

        const float tcx = T[0][j] * (1.f / S_GRID);
        const float tcy = T[1][j] * (1.f / S_GRID);
        const float tltx = tcx - 0.5f * T[2][j], trbx = tcx + 0.5f * T[2][j];
        const float tlty = tcy - 0.5f * T[3][j], trby = tcy + 0.5f * T[3][j];
        const float tarea = (trbx - tltx) * (trby - tlty);

        float iou0 = 0.f, iou1 = 0.f;
#pragma unroll
        for (int b = 0; b < 2; ++b) {
            const int o = 5 * b;
            const float pcx = P[o + 0][j] * (1.f / S_GRID);
            const float pcy = P[o + 1][j] * (1.f / S_GRID);
            const float pltx = pcx - 0.5f * P[o + 2][j], prbx = pcx + 0.5f * P[o + 2][j];
            const float plty = pcy - 0.5f * P[o + 3][j], prby = pcy + 0.5f * P[o + 3][j];
            const float ltx = fmaxf(tltx, pltx), rbx = fminf(trbx, prbx);
            const float lty = fmaxf(tlty, plty), rby = fminf(trby, prby);
            const float w = fmaxf(rbx - ltx, 0.f), h = fmaxf(rby - lty, 0.f);
            const float inter = w * h;
            const float parea = (prbx - pltx) * (prby - plty);
            const float uni = tarea + parea - inter;
            const float iou = inter / ((uni == 0.f) ? 1.f : uni);
            if (b == 0) iou0 = iou; else iou1 = iou;
        }

        const bool r = (iou1 > iou0);          // jnp.argmax: first max on tie
        const float miou = fmaxf(iou0, iou1);

        const float bpr0 = r ? P[5][j] : P[0][j];
        const float bpr1 = r ? P[6][j] : P[1][j];
        const float bpr2 = r ? P[7][j] : P[2][j];
        const float bpr3 = r ? P[8][j] : P[3][j];
        const float bpr4 = r ? P[9][j] : P[4][j];
        const float btr0 = r ? T[5][j] : T[0][j];
        const float btr1 = r ? T[6][j] : T[1][j];
        const float btr2 = r ? T[7][j] : T[2][j];
        const float btr3 = r ? T[8][j] : T[3][j];

        const float dx = bpr0 - btr0, dy = bpr1 - btr1;
        const float dw = bpr2 - btr2, dh = bpr3 - btr3;
        const float dxy = dx * dx + dy * dy;
        const float dwh = dw * dw + dh * dh;
        const float dconf = bpr4 - miou;

        total += obj * (LAMBDA_COORD * (dxy + dwh) + dconf * dconf)
               + LAMBDA_NOOBJ * noobj_term;
    }

#pragma unroll
    for (int off = 32; off > 0; off >>= 1)
        total += __shfl_down(total, off);
    __shared__ float wsum[4];
    if ((threadIdx.x & 63) == 0) wsum[threadIdx.x >> 6] = total;
    __syncthreads();
    if (threadIdx.x == 0)
        part[CLS_BLOCKS + blockIdx.x] = (wsum[0] + wsum[1]) + (wsum[2] + wsum[3]);
}

// ---------------- final reduce ----------------
__global__ __launch_bounds__(256) void reduce_kernel(
    const float* __restrict__ part, float* __restrict__ out)
{
    const int tid = threadIdx.x;
    float s = 0.f;
#pragma unroll
    for (int k = 0; k < 12; ++k) {
        const int i = tid + k * 256;
        if (i < NPART) s += part[i];
    }
#pragma unroll
    for (int off = 32; off > 0; off >>= 1)
        s += __shfl_down(s, off);
    __shared__ float w[4];
    if ((tid & 63) == 0) w[tid >> 6] = s;
    __syncthreads();
    if (tid == 0)
        out[0] = ((w[0] + w[1]) + (w[2] + w[3])) * (1.0f / N_BATCH);
}

extern "C" void kernel_launch(void* const* d_in, const int* in_sizes, int n_in,
                              void* d_out, int out_size, void* d_ws, size_t ws_size,
                              hipStream_t stream) {
    const float* pred = (const float*)d_in[0];
    const float* tgt  = (const float*)d_in[1];
    float* out  = (float*)d_out;
    float* part = (float*)d_ws;     // NPART floats of scratch

    hipLaunchKernelGGL(cls_kernel, dim3(CLS_BLOCKS), dim3(256), 0, stream,
                       pred, tgt, part);
    hipLaunchKernelGGL(box_kernel, dim3(BOX_BLOCKS), dim3(256), 0, stream,
                       pred, tgt, part);
    hipLaunchKernelGGL(reduce_kernel, dim3(1), dim3(256), 0, stream,
                       part, out);
}

// Round 7
// 211.923 us; speedup vs baseline: 1.0023x; 1.0023x over previous
//
#include <hip/hip_runtime.h>

// YOLO loss: pred/target (4096, 30, 14, 14) f32 -> scalar. ~193 MB read.
// R7: fuse cls-stream + box-gather into ONE dispatch (branch on blockIdx).
// R6 showed both kernels <56 us each but serialized on the stream; the
// harness's own fill proves 6.8 TB/s one-direction is possible, while every
// read kernel sits at ~2.7 TB/s logical. Fusing removes the inter-kernel
// bubble and gives one clean counter row to decide read-ceiling vs not.
//   blocks [0, 2048)       : class planes (129 MB) as grid-stride float4 stream
//   blocks [2048, 2832)    : box planes (64 MB) as per-cell-quad gather (R1 math)

#define S_GRID 14
#define SS 196              // S*S
#define N_BATCH 4096
#define QPI 1470            // quads per image (30 planes * 49)
#define CQ_PER_IMG 980      // class quads per image (planes 10..29)
#define NCQ (N_BATCH * CQ_PER_IMG)   // 4,014,080
#define NBQ (N_BATCH * 49)           // 200,704 box cell-quads
#define CLS_BLOCKS 2048
#define BOX_BLOCKS 784               // NBQ / 256 exactly
#define NPART (CLS_BLOCKS + BOX_BLOCKS)   // 2832
#define LAMBDA_COORD 5.0f
#define LAMBDA_NOOBJ 0.5f

__global__ __launch_bounds__(256) void yolo_fused_kernel(
    const float* __restrict__ pred,
    const float* __restrict__ tgt,
    float* __restrict__ part)
{
    const float4* pb4 = (const float4*)pred;
    const float4* tb4 = (const float4*)tgt;
    float total = 0.f;

    if (blockIdx.x < CLS_BLOCKS) {
        // ---------------- class part: pure grid-stride stream ----------------
        const int gtid   = blockIdx.x * 256 + threadIdx.x;
        const int stride = CLS_BLOCKS * 256;
        for (int q = gtid; q < NCQ; q += stride) {
            const int n  = q / CQ_PER_IMG;
            const int r  = q - n * CQ_PER_IMG;
            const int rq = r - 49 * (r / 49);          // quad within its plane
            const size_t base = (size_t)n * QPI;
            const float4 p = pb4[base + 490 + r];
            const float4 t = tb4[base + 490 + r];
            const float4 o = tb4[base + 196 + rq];     // tgt conf plane, L1-hot
            const float d0 = p.x - t.x, d1 = p.y - t.y;
            const float d2 = p.z - t.z, d3 = p.w - t.w;
            const float a0 = (o.x > 0.f) ? d0 * d0 : 0.f;
            const float a1 = (o.y > 0.f) ? d1 * d1 : 0.f;
            const float a2 = (o.z > 0.f) ? d2 * d2 : 0.f;
            const float a3 = (o.w > 0.f) ? d3 * d3 : 0.f;
            total += (a0 + a1) + (a2 + a3);
        }
    } else {
        // ---------------- box part: per-cell-quad gather (R1 math) ----------
        const int t  = (blockIdx.x - CLS_BLOCKS) * 256 + threadIdx.x;  // < NBQ
        const int n  = t / 49;
        const int q  = t - n * 49;

        const float4* pb = pb4 + (size_t)n * QPI + q;
        const float4* tb = tb4 + (size_t)n * QPI + q;

        float P[10][4], T[10][4];
#pragma unroll
        for (int d = 0; d < 10; ++d) {
            const float4 p  = pb[d * 49];
            const float4 tv = tb[d * 49];
            P[d][0] = p.x;  P[d][1] = p.y;  P[d][2] = p.z;  P[d][3] = p.w;
            T[d][0] = tv.x; T[d][1] = tv.y; T[d][2] = tv.z; T[d][3] = tv.w;
        }

#pragma unroll
        for (int j = 0; j < 4; ++j) {
            const float tconf = T[4][j];
            const float obj   = (tconf > 0.f)  ? 1.f : 0.f;
            const float noobj = (tconf == 0.f) ? 1.f : 0.f;

            const float dc0 = P[4][j] - T[4][j];
            const float dc1 = P[9][j] - T[9][j];
            const float noobj_term = noobj * (dc0 * dc0 + dc1 * dc1);

            const float tcx = T[0][j] * (1.f / S_GRID);
            const float tcy = T[1][j] * (1.f / S_GRID);
            const float tltx = tcx - 0.5f * T[2][j], trbx = tcx + 0.5f * T[2][j];
            const float tlty = tcy - 0.5f * T[3][j], trby = tcy + 0.5f * T[3][j];
            const float tarea = (trbx - tltx) * (trby - tlty);

            float iou0 = 0.f, iou1 = 0.f;
#pragma unroll
            for (int b = 0; b < 2; ++b) {
                const int o = 5 * b;
                const float pcx = P[o + 0][j] * (1.f / S_GRID);
                const float pcy = P[o + 1][j] * (1.f / S_GRID);
                const float pltx = pcx - 0.5f * P[o + 2][j], prbx = pcx + 0.5f * P[o + 2][j];
                const float plty = pcy - 0.5f * P[o + 3][j], prby = pcy + 0.5f * P[o + 3][j];
                const float ltx = fmaxf(tltx, pltx), rbx = fminf(trbx, prbx);
                const float lty = fmaxf(tlty, plty), rby = fminf(trby, prby);
                const float w = fmaxf(rbx - ltx, 0.f), h = fmaxf(rby - lty, 0.f);
                const float inter = w * h;
                const float parea = (prbx - pltx) * (prby - plty);
                const float uni = tarea + parea - inter;
                const float iou = inter / ((uni == 0.f) ? 1.f : uni);
                if (b == 0) iou0 = iou; else iou1 = iou;
            }

            const bool r = (iou1 > iou0);          // jnp.argmax: first max on tie
            const float miou = fmaxf(iou0, iou1);

            const float bpr0 = r ? P[5][j] : P[0][j];
            const float bpr1 = r ? P[6][j] : P[1][j];
            const float bpr2 = r ? P[7][j] : P[2][j];
            const float bpr3 = r ? P[8][j] : P[3][j];
            const float bpr4 = r ? P[9][j] : P[4][j];
            const float btr0 = r ? T[5][j] : T[0][j];
            const float btr1 = r ? T[6][j] : T[1][j];
            const float btr2 = r ? T[7][j] : T[2][j];
            const float btr3 = r ? T[8][j] : T[3][j];

            const float dx = bpr0 - btr0, dy = bpr1 - btr1;
            const float dw = bpr2 - btr2, dh = bpr3 - btr3;
            const float dxy = dx * dx + dy * dy;
            const float dwh = dw * dw + dh * dh;
            const float dconf = bpr4 - miou;

            total += obj * (LAMBDA_COORD * (dxy + dwh) + dconf * dconf)
                   + LAMBDA_NOOBJ * noobj_term;
        }
    }

    // ---- reduce: wave(64) shuffle -> LDS -> one plain store per block ----
#pragma unroll
    for (int off = 32; off > 0; off >>= 1)
        total += __shfl_down(total, off);
    __shared__ float wsum[4];
    if ((threadIdx.x & 63) == 0) wsum[threadIdx.x >> 6] = total;
    __syncthreads();
    if (threadIdx.x == 0)
        part[blockIdx.x] = (wsum[0] + wsum[1]) + (wsum[2] + wsum[3]);
}

// ---------------- final reduce ----------------
__global__ __launch_bounds__(256) void reduce_kernel(
    const float* __restrict__ part, float* __restrict__ out)
{
    const int tid = threadIdx.x;
    float s = 0.f;
#pragma unroll
    for (int k = 0; k < 12; ++k) {
        const int i = tid + k * 256;
        if (i < NPART) s += part[i];
    }
#pragma unroll
    for (int off = 32; off > 0; off >>= 1)
        s += __shfl_down(s, off);
    __shared__ float w[4];
    if ((tid & 63) == 0) w[tid >> 6] = s;
    __syncthreads();
    if (tid == 0)
        out[0] = ((w[0] + w[1]) + (w[2] + w[3])) * (1.0f / N_BATCH);
}

extern "C" void kernel_launch(void* const* d_in, const int* in_sizes, int n_in,
                              void* d_out, int out_size, void* d_ws, size_t ws_size,
                              hipStream_t stream) {
    const float* pred = (const float*)d_in[0];
    const float* tgt  = (const float*)d_in[1];
    float* out  = (float*)d_out;
    float* part = (float*)d_ws;     // NPART floats of scratch

    hipLaunchKernelGGL(yolo_fused_kernel, dim3(NPART), dim3(256), 0, stream,
                       pred, tgt, part);
    hipLaunchKernelGGL(reduce_kernel, dim3(1), dim3(256), 0, stream,
                       part, out);
}

// Round 8
// 194.320 us; speedup vs baseline: 1.0931x; 1.0906x over previous
//
#include <hip/hip_runtime.h>

// YOLO loss: pred/target (4096, 30, 14, 14) f32 -> scalar. ~193 MB read.
// R8: final lever test. Nine designs (R1-R7) all pin at 2.6-2.8 TB/s logical
// read regardless of structure; harness fill writes at 6.8 TB/s; R4's
// L3-resident dispatch ran no faster -> read-fill path (~2.7 TB/s chip-wide)
// is the suspected structural ceiling. This round: (a) non-temporal loads
// (nt flag, no L2 allocation) on all big streams - every byte is read once,
// so caching has no value; (b) division-free class loop (2 images per block,
// precomputed conf-quad offsets). If dur is unchanged, ceiling is confirmed.
//   blocks [0, 2048)    : class planes, 2 images/block, nt float4 stream
//   blocks [2048, 2832) : box planes, per-cell-quad nt gather (R1 math)

#define S_GRID 14
#define SS 196              // S*S
#define N_BATCH 4096
#define QPI 1470            // quads per image (30 planes * 49)
#define CLS_BLOCKS 2048     // 2 images per block
#define BOX_BLOCKS 784      // 200704 cell-quads / 256
#define NPART (CLS_BLOCKS + BOX_BLOCKS)   // 2832
#define LAMBDA_COORD 5.0f
#define LAMBDA_NOOBJ 0.5f

typedef float v4f __attribute__((ext_vector_type(4)));

__global__ __launch_bounds__(256) void yolo_fused_kernel(
    const float* __restrict__ pred,
    const float* __restrict__ tgt,
    float* __restrict__ part)
{
    const v4f* pv = (const v4f*)pred;
    const v4f* tv = (const v4f*)tgt;
    const int tid = threadIdx.x;
    float total = 0.f;

    if (blockIdx.x < CLS_BLOCKS) {
        // ------------- class part: 2 images/block, division-free -------------
        const int n0 = blockIdx.x * 2;
        int rq[4];                       // conf-plane quad for i = tid + 256k
#pragma unroll
        for (int k = 0; k < 4; ++k) {
            int i = tid + k * 256;
            rq[k] = i - 49 * (i / 49);   // computed once, not per load
        }
#pragma unroll
        for (int im = 0; im < 2; ++im) {
            const size_t base = (size_t)(n0 + im) * QPI;
            const v4f* pc = pv + base + 490;     // class quads (980)
            const v4f* tc = tv + base + 490;
            const v4f* oc = tv + base + 196;     // tgt conf plane (d=4)
#pragma unroll
            for (int k = 0; k < 4; ++k) {
                const int i = tid + k * 256;
                if (i < 980) {
                    const v4f p = __builtin_nontemporal_load(pc + i);
                    const v4f t = __builtin_nontemporal_load(tc + i);
                    const v4f o = oc[rq[k]];     // L1-hot, cacheable
                    const float d0 = p.x - t.x, d1 = p.y - t.y;
                    const float d2 = p.z - t.z, d3 = p.w - t.w;
                    const float a0 = (o.x > 0.f) ? d0 * d0 : 0.f;
                    const float a1 = (o.y > 0.f) ? d1 * d1 : 0.f;
                    const float a2 = (o.z > 0.f) ? d2 * d2 : 0.f;
                    const float a3 = (o.w > 0.f) ? d3 * d3 : 0.f;
                    total += (a0 + a1) + (a2 + a3);
                }
            }
        }
    } else {
        // ------------- box part: per-cell-quad nt gather (R1 math) ----------
        const int t  = (blockIdx.x - CLS_BLOCKS) * 256 + tid;   // < 200704
        const int n  = t / 49;
        const int q  = t - n * 49;

        const v4f* pb = pv + (size_t)n * QPI + q;
        const v4f* tb = tv + (size_t)n * QPI + q;

        float P[10][4], T[10][4];
#pragma unroll
        for (int d = 0; d < 10; ++d) {
            const v4f p  = __builtin_nontemporal_load(pb + d * 49);
            const v4f w  = __builtin_nontemporal_load(tb + d * 49);
            P[d][0] = p.x; P[d][1] = p.y; P[d][2] = p.z; P[d][3] = p.w;
            T[d][0] = w.x; T[d][1] = w.y; T[d][2] = w.z; T[d][3] = w.w;
        }

#pragma unroll
        for (int j = 0; j < 4; ++j) {
            const float tconf = T[4][j];
            const float obj   = (tconf > 0.f)  ? 1.f : 0.f;
            const float noobj = (tconf == 0.f) ? 1.f : 0.f;

            const float dc0 = P[4][j] - T[4][j];
            const float dc1 = P[9][j] - T[9][j];
            const float noobj_term = noobj * (dc0 * dc0 + dc1 * dc1);

            const float tcx = T[0][j] * (1.f / S_GRID);
            const float tcy = T[1][j] * (1.f / S_GRID);
            const float tltx = tcx - 0.5f * T[2][j], trbx = tcx + 0.5f * T[2][j];
            const float tlty = tcy - 0.5f * T[3][j], trby = tcy + 0.5f * T[3][j];
            const float tarea = (trbx - tltx) * (trby - tlty);

            float iou0 = 0.f, iou1 = 0.f;
#pragma unroll
            for (int b = 0; b < 2; ++b) {
                const int o = 5 * b;
                const float pcx = P[o + 0][j] * (1.f / S_GRID);
                const float pcy = P[o + 1][j] * (1.f / S_GRID);
                const float pltx = pcx - 0.5f * P[o + 2][j], prbx = pcx + 0.5f * P[o + 2][j];
                const float plty = pcy - 0.5f * P[o + 3][j], prby = pcy + 0.5f * P[o + 3][j];
                const float ltx = fmaxf(tltx, pltx), rbx = fminf(trbx, prbx);
                const float lty = fmaxf(tlty, plty), rby = fminf(trby, prby);
                const float w = fmaxf(rbx - ltx, 0.f), h = fmaxf(rby - lty, 0.f);
                const float inter = w * h;
                const float parea = (prbx - pltx) * (prby - plty);
                const float uni = tarea + parea - inter;
                const float iou = inter / ((uni == 0.f) ? 1.f : uni);
                if (b == 0) iou0 = iou; else iou1 = iou;
            }

            const bool r = (iou1 > iou0);          // jnp.argmax: first max on tie
            const float miou = fmaxf(iou0, iou1);

            const float bpr0 = r ? P[5][j] : P[0][j];
            const float bpr1 = r ? P[6][j] : P[1][j];
            const float bpr2 = r ? P[7][j] : P[2][j];
            const float bpr3 = r ? P[8][j] : P[3][j];
            const float bpr4 = r ? P[9][j] : P[4][j];
            const float btr0 = r ? T[5][j] : T[0][j];
            const float btr1 = r ? T[6][j] : T[1][j];
            const float btr2 = r ? T[7][j] : T[2][j];
            const float btr3 = r ? T[8][j] : T[3][j];

            const float dx = bpr0 - btr0, dy = bpr1 - btr1;
            const float dw = bpr2 - btr2, dh = bpr3 - btr3;
            const float dxy = dx * dx + dy * dy;
            const float dwh = dw * dw + dh * dh;
            const float dconf = bpr4 - miou;

            total += obj * (LAMBDA_COORD * (dxy + dwh) + dconf * dconf)
                   + LAMBDA_NOOBJ * noobj_term;
        }
    }

    // ---- reduce: wave(64) shuffle -> LDS -> one plain store per block ----
#pragma unroll
    for (int off = 32; off > 0; off >>= 1)
        total += __shfl_down(total, off);
    __shared__ float wsum[4];
    if ((tid & 63) == 0) wsum[tid >> 6] = total;
    __syncthreads();
    if (tid == 0)
        part[blockIdx.x] = (wsum[0] + wsum[1]) + (wsum[2] + wsum[3]);
}

// ---------------- final reduce ----------------
__global__ __launch_bounds__(256) void reduce_kernel(
    const float* __restrict__ part, float* __restrict__ out)
{
    const int tid = threadIdx.x;
    float s = 0.f;
#pragma unroll
    for (int k = 0; k < 12; ++k) {
        const int i = tid + k * 256;
        if (i < NPART) s += part[i];
    }
#pragma unroll
    for (int off = 32; off > 0; off >>= 1)
        s += __shfl_down(s, off);
    __shared__ float w[4];
    if ((tid & 63) == 0) w[tid >> 6] = s;
    __syncthreads();
    if (tid == 0)
        out[0] = ((w[0] + w[1]) + (w[2] + w[3])) * (1.0f / N_BATCH);
}

extern "C" void kernel_launch(void* const* d_in, const int* in_sizes, int n_in,
                              void* d_out, int out_size, void* d_ws, size_t ws_size,
                              hipStream_t stream) {
    const float* pred = (const float*)d_in[0];
    const float* tgt  = (const float*)d_in[1];
    float* out  = (float*)d_out;
    float* part = (float*)d_ws;     // NPART floats of scratch

    hipLaunchKernelGGL(yolo_fused_kernel, dim3(NPART), dim3(256), 0, stream,
                       pred, tgt, part);
    hipLaunchKernelGGL(reduce_kernel, dim3(1), dim3(256), 0, stream,
                       part, out);
}